// Round 7
// baseline (203.889 us; speedup 1.0000x reference)
//
#include <hip/hip_runtime.h>
#include <hip/hip_bf16.h>

// StochasticEnsemble: hard-routed 8-expert MLP.
// Round 7: gemm2 K-loop gets prefetch DISTANCE 2 (two register prefetch sets,
// manual unroll x2 so indices are compile-time). Convert at iter it waits only
// on loads issued at it-2 (~2 full iters in flight -> vmcnt(12)-style partial
// waits, covering L3/HBM latency). One barrier per iter, 2 LDS buffers.
// route/scan/gemm1 unchanged from round 6.

#define BATCH 2048
#define ZD 128
#define HID 1024
#define OUTD 3072
#define NEXP 8

#define TMG 128
#define TNG 128
#define BKG 64
#define MAXTF 24          // max 128-row M-tiles

typedef short bf16x8 __attribute__((ext_vector_type(8)));   // 8 bf16 = 4 VGPRs
typedef float f32x4 __attribute__((ext_vector_type(4)));

// ---- workspace byte layout (ws_size = 384 MiB) ----
// 0        counts[8]
// 64       ntl[1]
// 128      texp[24]
// 256      perm[3072]               -> ends 12544
// 12544    bucket[8*2048]           -> ends 78080
// 78080    zb bf16 [2048*128]       -> ends 602368
// 602368   Hb bf16 [3072*1024]      -> ends 6893824

__global__ __launch_bounds__(256) void route_kernel(const float* __restrict__ z,
                                                    __hip_bfloat16* __restrict__ zb,
                                                    int* counts, int* bucket) {
    __shared__ int lcnt[NEXP];
    __shared__ int gbase[NEXP];
    int t = threadIdx.x;
    if (t < NEXP) lcnt[t] = 0;
    __syncthreads();

    int s = blockIdx.x * 32 + (t >> 3);          // sample
    int li = t & 7;                               // lane-in-sample
    const float* zp = z + (size_t)s * ZD + li * 16;
    float sum = 0.f;
    union { bf16x8 v8; __hip_bfloat16 h[8]; } u0, u1;
#pragma unroll
    for (int i = 0; i < 4; i++) {
        float4 v = ((const float4*)zp)[i];
        sum += floorf(fabsf(v.x) * 1000.0f) + floorf(fabsf(v.y) * 1000.0f) +
               floorf(fabsf(v.z) * 1000.0f) + floorf(fabsf(v.w) * 1000.0f);
        __hip_bfloat16* dst = (i < 2) ? &u0.h[i * 4] : &u1.h[(i - 2) * 4];
        dst[0] = __float2bfloat16(v.x);
        dst[1] = __float2bfloat16(v.y);
        dst[2] = __float2bfloat16(v.z);
        dst[3] = __float2bfloat16(v.w);
    }
    bf16x8* zo = (bf16x8*)(zb + (size_t)s * ZD + li * 16);
    zo[0] = u0.v8;
    zo[1] = u1.v8;

    sum += __shfl_down(sum, 4);
    sum += __shfl_down(sum, 2);
    sum += __shfl_down(sum, 1);
    int e = 0, lpos = 0;
    if (li == 0) {
        e = ((int)sum) & 7;
        lpos = atomicAdd(&lcnt[e], 1);
    }
    __syncthreads();
    if (t < NEXP) gbase[t] = atomicAdd(&counts[t], lcnt[t]);
    __syncthreads();
    if (li == 0) bucket[e * BATCH + gbase[e] + lpos] = s;
}

__global__ void scan_kernel(const int* __restrict__ counts, int* ntl,
                            int* texp, int* perm, const int* __restrict__ bucket) {
    __shared__ int soff[NEXP + 1];
    __shared__ int scnt[NEXP];
    if (threadIdx.x == 0) {
        int o = 0;
        for (int e = 0; e < NEXP; e++) {
            scnt[e] = counts[e];
            soff[e] = o;
            o += (scnt[e] + TMG - 1) & ~(TMG - 1);
        }
        soff[NEXP] = o;
        *ntl = o / TMG;
    }
    __syncthreads();
    int total = soff[NEXP];
    for (int r = threadIdx.x; r < total; r += blockDim.x) {
        int e = 0;
        while (r >= soff[e + 1]) e++;
        int i = r - soff[e];
        perm[r] = (i < scnt[e]) ? bucket[e * BATCH + i] : -1;
        if ((r & (TMG - 1)) == 0) texp[r / TMG] = e;
    }
}

// ---------------- gemm1 (round-5 structure, K=128 = 2 iters) ----------------
__global__ __launch_bounds__(256, 3) void gemm1_fast(
    const __hip_bfloat16* __restrict__ zb, const float* __restrict__ W1,
    const float* __restrict__ b1, const int* __restrict__ ntl,
    const int* __restrict__ texp, const int* __restrict__ perm,
    __hip_bfloat16* __restrict__ H) {
    int mt = blockIdx.y;
    if (mt >= *ntl) return;
    int e = texp[mt];
    int n0 = blockIdx.x * TNG;

    __shared__ __align__(16) __hip_bfloat16 As[TMG * BKG];
    __shared__ __align__(16) __hip_bfloat16 Bs[TNG * BKG];
    __shared__ int rows_s[TMG];

    int tid = threadIdx.x;
    if (tid < TMG) rows_s[tid] = perm[mt * TMG + tid];
    __syncthreads();

    int lane = tid & 63, wave = tid >> 6;
    int cc = lane & 15, q = lane >> 4;
    int mw = (wave >> 1) * 64, nw = (wave & 1) * 64;

    int sr = tid >> 3, sc = tid & 7;
    int awbase = sr * 64 + (sc ^ (sr & 7)) * 8;     // + p*2048
    const __hip_bfloat16* Arp[4];
#pragma unroll
    for (int p = 0; p < 4; p++) {
        int r = rows_s[p * 32 + sr];
        if (r < 0) r = 0;
        Arp[p] = zb + (size_t)r * ZD + sc * 8;
    }
    int bkc = tid & 7, bn = (tid >> 3) * 4;
    const float* Bgf = W1 + (size_t)e * ZD * HID + (size_t)(bkc * 8) * HID + n0 + bn;
    int bwb[4];
#pragma unroll
    for (int j = 0; j < 4; j++)
        bwb[j] = (bn + j) * 64 + ((bkc ^ ((bn + j) & 7))) * 8;

    int A0 = (mw + cc) * 64, B0 = (nw + cc) * 64;
    int X0 = (q ^ (cc & 7)) * 8, X1 = ((4 + q) ^ (cc & 7)) * 8;

    float bias[4];
#pragma unroll
    for (int j = 0; j < 4; j++) bias[j] = b1[(size_t)e * HID + n0 + nw + j * 16 + cc];

    f32x4 zero4 = {0.f, 0.f, 0.f, 0.f};
    f32x4 acc[4][4];
#pragma unroll
    for (int i = 0; i < 4; i++)
#pragma unroll
        for (int j = 0; j < 4; j++) acc[i][j] = zero4;

    bf16x8 ga[4];
    union { bf16x8 v8; __hip_bfloat16 h[8]; } gb[4];
#pragma unroll
    for (int p = 0; p < 4; p++) ga[p] = *(const bf16x8*)(Arp[p]);
#pragma unroll
    for (int i = 0; i < 8; i++) {
        float4 v = *(const float4*)(Bgf + (size_t)i * HID);
        gb[0].h[i] = __float2bfloat16(v.x);
        gb[1].h[i] = __float2bfloat16(v.y);
        gb[2].h[i] = __float2bfloat16(v.z);
        gb[3].h[i] = __float2bfloat16(v.w);
    }
#pragma unroll
    for (int it = 0; it < ZD / BKG; ++it) {
        __syncthreads();
#pragma unroll
        for (int p = 0; p < 4; p++) *(bf16x8*)(As + awbase + p * 2048) = ga[p];
#pragma unroll
        for (int j = 0; j < 4; j++) *(bf16x8*)(Bs + bwb[j]) = gb[j].v8;
        __syncthreads();
        if (it + 1 < ZD / BKG) {
#pragma unroll
            for (int p = 0; p < 4; p++)
                ga[p] = *(const bf16x8*)(Arp[p] + (it + 1) * BKG);
#pragma unroll
            for (int i = 0; i < 8; i++) {
                float4 v = *(const float4*)(Bgf + (size_t)((it + 1) * BKG + i) * HID);
                gb[0].h[i] = __float2bfloat16(v.x);
                gb[1].h[i] = __float2bfloat16(v.y);
                gb[2].h[i] = __float2bfloat16(v.z);
                gb[3].h[i] = __float2bfloat16(v.w);
            }
        }
#pragma unroll
        for (int kh = 0; kh < 2; ++kh) {
            int X = kh ? X1 : X0;
            bf16x8 af[4], bfr[4];
#pragma unroll
            for (int i = 0; i < 4; i++) af[i] = *(const bf16x8*)(As + A0 + i * 1024 + X);
#pragma unroll
            for (int j = 0; j < 4; j++) bfr[j] = *(const bf16x8*)(Bs + B0 + j * 1024 + X);
#pragma unroll
            for (int i = 0; i < 4; i++)
#pragma unroll
                for (int j = 0; j < 4; j++)
                    acc[i][j] = __builtin_amdgcn_mfma_f32_16x16x32_bf16(af[i], bfr[j],
                                                                        acc[i][j], 0, 0, 0);
        }
    }
#pragma unroll
    for (int i = 0; i < 4; i++)
#pragma unroll
        for (int r = 0; r < 4; r++) {
            int m = mw + i * 16 + q * 4 + r;
            __hip_bfloat16* hp = H + (size_t)(mt * TMG + m) * HID + n0 + nw + cc;
#pragma unroll
            for (int j = 0; j < 4; j++)
                hp[j * 16] = __float2bfloat16(fmaxf(acc[i][j][r] + bias[j], 0.f));
        }
}

// ---------------- gemm2: distance-2 prefetch, 1 barrier/iter ----------------
// PIPE(S, IT): convert+write prefetch set S (loaded at IT-2) into LDS buf S;
// issue loads for IT+2 into set S; barrier; MFMA from buf S.
#define PIPE(S, IT)                                                            \
    {                                                                          \
        __hip_bfloat16* Ac = As[S];                                           \
        __hip_bfloat16* Bc = Bs[S];                                           \
        union { bf16x8 v8; __hip_bfloat16 h[8]; } gbv[4];                     \
        _Pragma("unroll")                                                      \
        for (int i = 0; i < 8; i++) {                                          \
            gbv[0].h[i] = __float2bfloat16(braw[S][i].x);                      \
            gbv[1].h[i] = __float2bfloat16(braw[S][i].y);                      \
            gbv[2].h[i] = __float2bfloat16(braw[S][i].z);                      \
            gbv[3].h[i] = __float2bfloat16(braw[S][i].w);                      \
        }                                                                      \
        _Pragma("unroll")                                                      \
        for (int p = 0; p < 4; p++) *(bf16x8*)(Ac + awbase + p * 2048) = ga[S][p]; \
        _Pragma("unroll")                                                      \
        for (int j = 0; j < 4; j++) *(bf16x8*)(Bc + bwb[j]) = gbv[j].v8;       \
        if ((IT) + 2 < NIT) {                                                  \
            int k2 = ((IT) + 2) * BKG;                                         \
            _Pragma("unroll")                                                  \
            for (int p = 0; p < 4; p++)                                        \
                ga[S][p] = *(const bf16x8*)(Ag + (size_t)p * 32 * HID + k2);   \
            _Pragma("unroll")                                                  \
            for (int i = 0; i < 8; i++)                                        \
                braw[S][i] = *(const float4*)(Bgf + (size_t)(k2 + i) * OUTD);  \
        }                                                                      \
        __syncthreads();                                                       \
        _Pragma("unroll")                                                      \
        for (int kh = 0; kh < 2; ++kh) {                                       \
            int X = kh ? X1 : X0;                                              \
            bf16x8 af[4], bfr[4];                                              \
            _Pragma("unroll")                                                  \
            for (int i = 0; i < 4; i++) af[i] = *(const bf16x8*)(Ac + A0 + i * 1024 + X); \
            _Pragma("unroll")                                                  \
            for (int j = 0; j < 4; j++) bfr[j] = *(const bf16x8*)(Bc + B0 + j * 1024 + X); \
            _Pragma("unroll")                                                  \
            for (int i = 0; i < 4; i++)                                        \
                _Pragma("unroll")                                              \
                for (int j = 0; j < 4; j++)                                    \
                    acc[i][j] = __builtin_amdgcn_mfma_f32_16x16x32_bf16(       \
                        af[i], bfr[j], acc[i][j], 0, 0, 0);                    \
        }                                                                      \
    }

__global__ __launch_bounds__(256, 2) void gemm2_fast(
    const __hip_bfloat16* __restrict__ H, const float* __restrict__ W2,
    const float* __restrict__ b2, const int* __restrict__ ntl,
    const int* __restrict__ texp, const int* __restrict__ perm,
    float* __restrict__ out) {
    int mt = blockIdx.y;
    if (mt >= *ntl) return;
    int e = texp[mt];
    int n0 = blockIdx.x * TNG;

    __shared__ __align__(16) __hip_bfloat16 As[2][TMG * BKG];   // 2 x 16 KB
    __shared__ __align__(16) __hip_bfloat16 Bs[2][TNG * BKG];   // 2 x 16 KB
    __shared__ int rows_s[TMG];

    int tid = threadIdx.x;
    if (tid < TMG) rows_s[tid] = perm[mt * TMG + tid];

    int lane = tid & 63, wave = tid >> 6;
    int cc = lane & 15, q = lane >> 4;
    int mw = (wave >> 1) * 64, nw = (wave & 1) * 64;

    int sr = tid >> 3, sc = tid & 7;
    int awbase = sr * 64 + (sc ^ (sr & 7)) * 8;     // + p*2048
    const __hip_bfloat16* Ag = H + ((size_t)mt * TMG + sr) * HID + sc * 8;
    int bkc = tid & 7, bn = (tid >> 3) * 4;
    const float* Bgf = W2 + (size_t)e * HID * OUTD + (size_t)(bkc * 8) * OUTD + n0 + bn;
    int bwb[4];
#pragma unroll
    for (int j = 0; j < 4; j++)
        bwb[j] = (bn + j) * 64 + ((bkc ^ ((bn + j) & 7))) * 8;

    int A0 = (mw + cc) * 64, B0 = (nw + cc) * 64;
    int X0 = (q ^ (cc & 7)) * 8, X1 = ((4 + q) ^ (cc & 7)) * 8;

    float bias[4];
#pragma unroll
    for (int j = 0; j < 4; j++) bias[j] = b2[(size_t)e * OUTD + n0 + nw + j * 16 + cc];

    f32x4 zero4 = {0.f, 0.f, 0.f, 0.f};
    f32x4 acc[4][4];
#pragma unroll
    for (int i = 0; i < 4; i++)
#pragma unroll
        for (int j = 0; j < 4; j++) acc[i][j] = zero4;

    const int NIT = HID / BKG;   // 16 (even)

    // distance-2 prefetch: set 0 <- k=0, set 1 <- k=BKG
    bf16x8 ga[2][4];
    float4 braw[2][8];
#pragma unroll
    for (int s = 0; s < 2; s++) {
#pragma unroll
        for (int p = 0; p < 4; p++)
            ga[s][p] = *(const bf16x8*)(Ag + (size_t)p * 32 * HID + s * BKG);
#pragma unroll
        for (int i = 0; i < 8; i++)
            braw[s][i] = *(const float4*)(Bgf + (size_t)(s * BKG + i) * OUTD);
    }

    for (int it = 0; it < NIT; it += 2) {
        PIPE(0, it);
        PIPE(1, it + 1);
    }

#pragma unroll
    for (int i = 0; i < 4; i++)
#pragma unroll
        for (int r = 0; r < 4; r++) {
            int m = mw + i * 16 + q * 4 + r;
            int orow = rows_s[m];
            if (orow >= 0) {
                float* op = out + (size_t)orow * OUTD + n0 + nw + cc;
#pragma unroll
                for (int j = 0; j < 4; j++) op[j * 16] = acc[i][j][r] + bias[j];
            }
        }
}

extern "C" void kernel_launch(void* const* d_in, const int* in_sizes, int n_in,
                              void* d_out, int out_size, void* d_ws, size_t ws_size,
                              hipStream_t stream) {
    const float* z  = (const float*)d_in[0];
    const float* W1 = (const float*)d_in[1];
    const float* b1 = (const float*)d_in[2];
    const float* W2 = (const float*)d_in[3];
    const float* b2 = (const float*)d_in[4];
    float* out = (float*)d_out;

    char* ws = (char*)d_ws;
    int* counts = (int*)ws;
    int* ntl    = (int*)(ws + 64);
    int* texp   = (int*)(ws + 128);
    int* perm   = (int*)(ws + 256);
    int* bucket = (int*)(ws + 12544);
    __hip_bfloat16* zb  = (__hip_bfloat16*)(ws + 78080);
    __hip_bfloat16* Hb  = (__hip_bfloat16*)(ws + 602368);

    hipMemsetAsync(counts, 0, 64, stream);
    hipLaunchKernelGGL(route_kernel, dim3(BATCH / 32), dim3(256), 0, stream,
                       z, zb, counts, bucket);
    hipLaunchKernelGGL(scan_kernel, dim3(1), dim3(256), 0, stream,
                       counts, ntl, texp, perm, bucket);
    hipLaunchKernelGGL(gemm1_fast, dim3(HID / TNG, MAXTF), dim3(256), 0, stream,
                       zb, W1, b1, ntl, texp, perm, Hb);
    hipLaunchKernelGGL(gemm2_fast, dim3(OUTD / TNG, MAXTF), dim3(256), 0, stream,
                       Hb, W2, b2, ntl, texp, perm, out);
}